// Round 1
// baseline (481.094 us; speedup 1.0000x reference)
//
#include <hip/hip_runtime.h>

// HBMA fused: full-search block matching (16x16 blocks, +/-4 search) + predicted
// frame gather. N=8, C=3, H=W=1024.
//
// Decomposition: one 64-thread workgroup (1 wave) per 64-wide x 16-tall strip
// (= 4 blocks side by side). Lane = column within strip. Ref halo strip
// (3 x 24 x 72, zero padded at image borders) staged in LDS; target rows kept
// in registers with compile-time indexing. Per-lane SAD accumulators
// acc[9][9] (dy,dx), reduced across each 16-lane group via __shfl_xor tree,
// then per-group argmin (ascending disp index, strict <, matching reference
// tie-break), then gather predicted pixels straight from the LDS ref strip.

namespace {
constexpr int BLKi  = 16;
constexpr int NSDi  = 4;
constexpr int ND    = 2 * NSDi + 1;        // 9 displacements per axis
constexpr int Nn    = 8;
constexpr int Cc    = 3;
constexpr int Hh    = 1024;
constexpr int Ww    = 1024;
constexpr int BHn   = Hh / BLKi;           // 64
constexpr int BWn   = Ww / BLKi;           // 64
constexpr int STRIPW = 64;                 // columns handled per wave
constexpr int NSTRIP = Ww / STRIPW;        // 16
constexpr int REFW  = STRIPW + 2 * NSDi;   // 72
constexpr int REFH  = BLKi + 2 * NSDi;     // 24
constexpr int REF_ELEMS = Cc * REFH * REFW; // 5184 (divisible by 64 -> 81 iters)
constexpr int MV_SIZE = Nn * 2 * BHn * BWn; // 65536
}

__global__ void zero_mv_kernel(float* __restrict__ out) {
    int i = blockIdx.x * 256 + threadIdx.x;
    if (i < MV_SIZE) out[i] = 0.0f;
}

__global__ __launch_bounds__(64) void hbma_kernel(
        const float* __restrict__ ref,
        const float* __restrict__ tgt,
        float* __restrict__ pred) {
    __shared__ float ldsR[REF_ELEMS];

    const int lane = (int)threadIdx.x;          // 0..63 = column within strip
    const int b    = (int)blockIdx.x;           // 0..8191
    const int n    = b >> 10;                   // 1024 strips per batch image
    const int rem  = b & 1023;
    const int Y0   = (rem >> 4) * BLKi;         // block-row * 16
    const int X0   = (rem & 15) * STRIPW;       // strip * 64
    const size_t fbase = (size_t)n * Cc * Hh * Ww;

    // ---- stage zero-padded ref strip: [c][r(24)][col(72)] ----
    #pragma unroll
    for (int t = 0; t < REF_ELEMS / 64; ++t) {
        int idx = t * 64 + lane;
        int c   = idx / (REFH * REFW);
        int r2  = idx - c * (REFH * REFW);
        int r   = r2 / REFW;
        int col = r2 - r * REFW;
        int gy  = Y0 - NSDi + r;
        int gx  = X0 - NSDi + col;
        float v = 0.0f;
        if ((unsigned)gy < (unsigned)Hh && (unsigned)gx < (unsigned)Ww)
            v = ref[fbase + ((size_t)c * Hh + gy) * Ww + gx];
        ldsR[idx] = v;
    }
    __syncthreads();

    // ---- SAD accumulation ----
    // acc[o][d] corresponds to dy = 4 - o, dx = d - 4
    float acc[ND][ND];
    #pragma unroll
    for (int o = 0; o < ND; ++o)
        #pragma unroll
        for (int d = 0; d < ND; ++d) acc[o][d] = 0.0f;

    for (int c = 0; c < Cc; ++c) {
        // target rows for this channel, lane's column (registers, static idx)
        float T[BLKi];
        #pragma unroll
        for (int y = 0; y < BLKi; ++y)
            T[y] = tgt[fbase + ((size_t)c * Hh + (Y0 + y)) * Ww + X0 + lane];

        #pragma unroll
        for (int rp = 0; rp < REFH; ++rp) {       // ref row index in strip
            float rv[ND];
            #pragma unroll
            for (int d = 0; d < ND; ++d)
                rv[d] = ldsR[(c * REFH + rp) * REFW + lane + d];
            #pragma unroll
            for (int o = 0; o < ND; ++o) {
                const int y = rp - 2 * NSDi + o;  // compile-time after unroll
                if (y >= 0 && y < BLKi) {
                    float tv = T[y];
                    #pragma unroll
                    for (int d = 0; d < ND; ++d)
                        acc[o][d] += fabsf(rv[d] - tv);
                }
            }
        }
    }

    // ---- reduce across the 16 lanes of each block group ----
    #pragma unroll
    for (int m = 1; m <= 8; m <<= 1) {
        #pragma unroll
        for (int o = 0; o < ND; ++o)
            #pragma unroll
            for (int d = 0; d < ND; ++d)
                acc[o][d] += __shfl_xor(acc[o][d], m, 64);
    }

    // ---- argmin over 81 disps, ascending reference index i=(8-o)*9+d,
    //      strict < so first (lowest i) wins ties, matching jax scan ----
    float best = acc[ND - 1][0];
    int bdy = -NSDi, bdx = -NSDi;
    #pragma unroll
    for (int o = ND - 1; o >= 0; --o) {
        #pragma unroll
        for (int d = 0; d < ND; ++d) {
            if (o == ND - 1 && d == 0) continue;
            if (acc[o][d] < best) {
                best = acc[o][d];
                bdy  = NSDi - o;
                bdx  = d - NSDi;
            }
        }
    }

    // ---- gather predicted frame from LDS ref strip (zero padded) ----
    const int gcol = lane + bdx + NSDi;           // 0..71
    for (int c = 0; c < Cc; ++c) {
        #pragma unroll
        for (int y = 0; y < BLKi; ++y) {
            float v = ldsR[(c * REFH + (y + bdy + NSDi)) * REFW + gcol];
            pred[fbase + ((size_t)c * Hh + (Y0 + y)) * Ww + X0 + lane] = v;
        }
    }
}

extern "C" void kernel_launch(void* const* d_in, const int* in_sizes, int n_in,
                              void* d_out, int out_size, void* d_ws, size_t ws_size,
                              hipStream_t stream) {
    const float* ref = (const float*)d_in[0];
    const float* tgt = (const float*)d_in[1];
    float* out = (float*)d_out;

    zero_mv_kernel<<<dim3((MV_SIZE + 255) / 256), dim3(256), 0, stream>>>(out);

    const int nblocks = Nn * BHn * NSTRIP;  // 8 * 64 * 16 = 8192
    hbma_kernel<<<dim3(nblocks), dim3(64), 0, stream>>>(ref, tgt, out + MV_SIZE);
}